// Round 3
// baseline (2710.970 us; speedup 1.0000x reference)
//
#include <hip/hip_runtime.h>
#include <hip/hip_bf16.h>

// Problem dims (fixed by the reference)
#define T_DIM 8192
#define D_DIM 4096
#define H_DIM 11008

typedef __attribute__((ext_vector_type(8))) __bf16 bf16x8;
typedef __attribute__((ext_vector_type(4))) float f32x4;
typedef __attribute__((ext_vector_type(16))) float f32x16;

typedef __attribute__((address_space(1))) const void gvoid_t;
typedef __attribute__((address_space(3))) void lvoid_t;

__device__ __forceinline__ void async_lds16(const void* g, void* l) {
    // 16B per lane, LDS dest = wave-uniform base + lane*16
    __builtin_amdgcn_global_load_lds((gvoid_t*)g, (lvoid_t*)l, 16, 0, 0);
}

__device__ const float NF4_TAB[16] = {
    -1.0f, -0.6961928009986877f, -0.5250730514526367f, -0.39491748809814453f,
    -0.28444138169288635f, -0.18477343022823334f, -0.09105003625154495f, 0.0f,
    0.07958029955625534f, 0.16093020141124725f, 0.24611230194568634f,
    0.33791524171829224f, 0.44070982933044434f, 0.5626170039176941f,
    0.7229568362236023f, 1.0f};

// ---------------- dequant: int32 codes + per-64 scalers -> bf16 ----------------
__global__ void dequant_nf4_kernel(const int* __restrict__ codes,
                                   const float* __restrict__ scalers,
                                   __bf16* __restrict__ out, long n) {
    __shared__ float tbl[16];
    if (threadIdx.x < 16) tbl[threadIdx.x] = NF4_TAB[threadIdx.x];
    __syncthreads();
    long i = ((long)blockIdx.x * blockDim.x + threadIdx.x) * 8;
    if (i >= n) return;
    float s = scalers[i >> 6];
    const int4* cp = (const int4*)(codes + i);
    int4 c0 = cp[0], c1 = cp[1];
    bf16x8 v;
    v[0] = (__bf16)(tbl[c0.x] * s);
    v[1] = (__bf16)(tbl[c0.y] * s);
    v[2] = (__bf16)(tbl[c0.z] * s);
    v[3] = (__bf16)(tbl[c0.w] * s);
    v[4] = (__bf16)(tbl[c1.x] * s);
    v[5] = (__bf16)(tbl[c1.y] * s);
    v[6] = (__bf16)(tbl[c1.z] * s);
    v[7] = (__bf16)(tbl[c1.w] * s);
    *(bf16x8*)(out + i) = v;
}

// ---------------- x: fp32 -> bf16 ----------------
__global__ void cvt_f32_bf16(const float* __restrict__ x, __bf16* __restrict__ out, long n) {
    long i = ((long)blockIdx.x * blockDim.x + threadIdx.x) * 8;
    if (i >= n) return;
    const float4* xp = (const float4*)(x + i);
    float4 f0 = xp[0], f1 = xp[1];
    bf16x8 v;
    v[0] = (__bf16)f0.x; v[1] = (__bf16)f0.y; v[2] = (__bf16)f0.z; v[3] = (__bf16)f0.w;
    v[4] = (__bf16)f1.x; v[5] = (__bf16)f1.y; v[6] = (__bf16)f1.z; v[7] = (__bf16)f1.w;
    *(bf16x8*)(out + i) = v;
}

// ============================================================================
// 256-wide deep-pipelined NT GEMM, 32x32x16 MFMA version.
//   A [M,K] K-major, B [N,K] K-major, BK=64, 8 waves (2M x 4N), per-wave
//   output 128x64 = 4(mt) x 2(nt) tiles of 32x32, 4 k-steps (kk) of 16.
//   LDS 128 KiB = 2 bufs x (A[256][64] + B[256][64]) bf16, XOR-swizzled 16B
//   blocks (block ^= row&7, applied on the pre-swizzled GLOBAL source of
//   global_load_lds; reads apply the same XOR). Frag rows are 32-aligned so
//   row&7 == lane&7 -> conflict-free ds_read_b128 (0 conflicts measured R2).
//
// Per K-tile (buf X), 3 regions (16/8/8 MFMA per wave):
//  R1: ds_read kk0,kk1 (12) | stage B1(t+1)->bufY | BAR lgk0 | 16 MFMA | BAR
//  R2: ds_read kk2,kk3 (12) |                       BAR lgk0 |  8 MFMA kk2 | BAR
//  R3: stage A0,A1(t+2)->bufX | 8 MFMA kk3 | stage B0(t+2)->bufX | vmcnt(6) BAR
// Stage safety: every stage targets a region whose ds_reads were drained by a
// per-wave lgkmcnt(0) BEFORE a barrier that precedes the stage issue.
// vmcnt(6) = exactly 3 half-tiles (6 loads) in flight (ledger: 16 outstanding
// at the wait; oldest 10 retired covers all of tile t+1).
//
// SILU=1 (fused gate): B-tile rows interleave w1/w2 every 32 rows:
//   tile-row R <- mat=(R>>5)&1 ? B2 : B1, col = n0 + 32*(R>>6) + (R&31)
// so wave wn's nt=0 tile accumulates x@w1^T and nt=1 x@w2^T for the SAME
// output columns n0+wn*32+(lane&31) -> epilogue silu(a1)*a2 is thread-local.
// Output tile 256x128 (n0 = bx*128).
//
// Block remap: XCD-chunked (bid0&7 -> xcd) AND bx-major within each chunk
// (by = xcd*4 + j%4, bx = j/4): each B panel is fetched once per XCD and
// reused 4x from L2; 8 XCDs stay phase-coherent on the same bx band so L3
// serves most B traffic. Requires nwg%8==0 and (nwg/8)%gridDim.x==0
// (fused: 2752/8/86=4; out-proj: 512/8/16=4).
// ============================================================================
template<int KD, int SILU, typename OutT>
__global__ __launch_bounds__(512, 2) void gemm_nt(
    const __bf16* __restrict__ A, const __bf16* __restrict__ B1,
    const __bf16* __restrict__ B2, OutT* __restrict__ Out, const int N)
{
    static_assert(KD % 128 == 0, "need an even number of K-tiles");
    __shared__ __bf16 lds[2 * 2 * 256 * 64];   // 128 KiB

    const int tid  = threadIdx.x;
    const int lane = tid & 63;
    const int wave = tid >> 6;        // 0..7
    const int wm = wave >> 2;         // 0..1 (M half)
    const int wn = wave & 3;          // 0..3 (N quarter)

    // XCD-chunked + bx-major remap (L2 B-panel reuse x4)
    const int nwg  = gridDim.x * gridDim.y;
    const int bid0 = blockIdx.y * gridDim.x + blockIdx.x;
    const int q    = nwg >> 3;                 // blocks per XCD chunk
    const int Rr   = q / gridDim.x;            // tile-rows per chunk (=4 here)
    const int xcd  = bid0 & 7;
    const int j    = bid0 >> 3;
    const int by   = xcd * Rr + (j % Rr);
    const int bx   = j / Rr;
    const long m0 = (long)by * 256;
    const long n0 = (long)bx * (SILU ? 128 : 256);

    // ---- staging addressing (pre-swizzled global source, linear LDS dest) ----
    const int sr = tid >> 3;                    // row within 64-row group
    const int sb = (tid & 7) ^ (sr & 7);        // swizzled global 16B block
    const __bf16* Arow = A + (m0 + sr) * (long)KD + sb * 8;
    const __bf16* Brow;
    if (SILU) {
        // LDS B row R = H*128 + a*64 + sr ; mat=(R>>5)&1 = sr&32 ;
        // col = n0 + 32*(R>>6) + (R&31) = n0 + (sr&31) + 32*(2H+a)
        const __bf16* matp = (sr & 32) ? B2 : B1;
        Brow = matp + (n0 + (sr & 31)) * (long)KD + sb * 8;
    } else {
        Brow = B1 + (n0 + sr) * (long)KD + sb * 8;
    }
    __bf16* dstA = &lds[(wave << 3) * 64];      // wave-uniform; +buf*32768 +h*8192
    __bf16* dstB = dstA + 16384;

    const long BH = (SILU ? 64 : 128) * (long)KD;  // B source: half-tile stride
    const long BA = (SILU ? 32 : 64) * (long)KD;   // B source: intra-half stride

#define STAGE_A(BUF, H, KT) do { \
        const __bf16* s_ = Arow + (long)(H) * 128 * KD + (long)(KT) * 64; \
        __bf16* d_ = dstA + (BUF) * 32768 + (H) * 8192; \
        async_lds16(s_, d_); \
        async_lds16(s_ + 64 * (long)KD, d_ + 4096); \
    } while (0)
#define STAGE_B(BUF, H, KT) do { \
        const __bf16* s_ = Brow + (long)(H) * BH + (long)(KT) * 64; \
        __bf16* d_ = dstB + (BUF) * 32768 + (H) * 8192; \
        async_lds16(s_, d_); \
        async_lds16(s_ + BA, d_ + 4096); \
    } while (0)

    // ---- fragment read addressing (32x32x16) ----
    // A row = wm*128 + mt*32 + (lane&31); k 16B-block g = kk*2 + (lane>>5);
    // physical block = g ^ (row&7) = g ^ (lane&7)
    const int l31 = lane & 31;
    const int gh  = lane >> 5;
    const int l7  = lane & 7;
    const int aOff = (wm * 128 + l31) * 64;
    const int bOff = 16384 + (wn * 64 + l31) * 64;

    auto rdA = [&](int buf, int mt, int kk) -> bf16x8 {
        return *(const bf16x8*)&lds[buf * 32768 + aOff + mt * 2048 +
                                    (((kk * 2 + gh) ^ l7) << 3)];
    };
    auto rdB = [&](int buf, int nt, int kk) -> bf16x8 {
        return *(const bf16x8*)&lds[buf * 32768 + bOff + nt * 2048 +
                                    (((kk * 2 + gh) ^ l7) << 3)];
    };

    f32x16 acc[4][2];
    const f32x16 z16 = {0.f,0.f,0.f,0.f,0.f,0.f,0.f,0.f,
                        0.f,0.f,0.f,0.f,0.f,0.f,0.f,0.f};
#pragma unroll
    for (int m = 0; m < 4; ++m)
#pragma unroll
        for (int n = 0; n < 2; ++n) acc[m][n] = z16;

    bf16x8 aF[4][4];   // [mt][kk]
    bf16x8 bF[2][4];   // [nt][kk]

#define LOAD_AB(BUF, P) { _Pragma("unroll") for (int c_ = 0; c_ < 2; ++c_) { \
        const int kk_ = 2 * (P) + c_; \
        _Pragma("unroll") for (int m_ = 0; m_ < 4; ++m_) \
            aF[m_][kk_] = rdA(BUF, m_, kk_); \
        _Pragma("unroll") for (int n_ = 0; n_ < 2; ++n_) \
            bF[n_][kk_] = rdB(BUF, n_, kk_); } }
#define MFMA8(KK) { _Pragma("unroll") for (int m_ = 0; m_ < 4; ++m_) \
        _Pragma("unroll") for (int n_ = 0; n_ < 2; ++n_) \
            acc[m_][n_] = __builtin_amdgcn_mfma_f32_32x32x16_bf16( \
                aF[m_][(KK)], bF[n_][(KK)], acc[m_][n_], 0, 0, 0); }
#define BAR()  __builtin_amdgcn_s_barrier()
#define LGK0() asm volatile("s_waitcnt lgkmcnt(0)" ::: "memory")
#define VM6()  asm volatile("s_waitcnt vmcnt(6)" ::: "memory")
#define PRIO1() __builtin_amdgcn_s_setprio(1)
#define PRIO0() __builtin_amdgcn_s_setprio(0)

    // One K-tile in BUF; stages B1(T1)->other buf, A+B0(T2)->BUF.
    // vmcnt(6) leaves exactly {A0,A1,B0}(T2) = 6 loads in flight.
#define TILE(BUF, T1, T2) \
    LOAD_AB(BUF, 0); \
    STAGE_B(1 - (BUF), 1, T1); \
    BAR(); LGK0(); PRIO1(); MFMA8(0); MFMA8(1); PRIO0(); BAR(); \
    LOAD_AB(BUF, 1); \
    BAR(); LGK0(); PRIO1(); MFMA8(2); PRIO0(); BAR(); \
    STAGE_A(BUF, 0, T2); STAGE_A(BUF, 1, T2); \
    PRIO1(); MFMA8(3); PRIO0(); \
    STAGE_B(BUF, 0, T2); \
    VM6(); BAR();

    const int NT = KD / 64;

    // ---- prologue: tile0 complete -> buf0; A0,A1,B0 of tile1 -> buf1 ----
    STAGE_A(0, 0, 0); STAGE_A(0, 1, 0);
    STAGE_B(0, 0, 0); STAGE_B(0, 1, 0);
    STAGE_A(1, 0, 1); STAGE_A(1, 1, 1);
    STAGE_B(1, 0, 1);
    VM6();            // 14 issued, drain to 6 -> tile0's 8 loads landed
    BAR();

#pragma unroll 1
    for (int t = 0; t < NT; t += 2) {
        const int t1 = t + 1;
        int t2 = t + 2; if (t2 >= NT) t2 -= NT;   // wrap: tail prefetch is
        int t3 = t + 3; if (t3 >= NT) t3 -= NT;   // harmless (never read)
        TILE(0, t1, t2);
        TILE(1, t2, t3);
    }
    asm volatile("s_waitcnt vmcnt(0)" ::: "memory");  // drain tail prefetches

    // ---- epilogue: 32x32 C/D layout col=lane&31, row=(reg&3)+8*(reg>>2)+4*(lane>>5)
    if (SILU) {
#pragma unroll
        for (int mt = 0; mt < 4; ++mt)
#pragma unroll
            for (int r = 0; r < 16; ++r) {
                const long row = m0 + wm * 128 + mt * 32 + (r & 3) + 8 * (r >> 2) + 4 * gh;
                const long idx = row * (long)N + (n0 + wn * 32 + l31);
                float a = acc[mt][0][r];      // x @ w1^T
                float b = acc[mt][1][r];      // x @ w2^T
                float sg = 1.0f / (1.0f + __expf(-a));
                Out[idx] = (OutT)(a * sg * b);
            }
    } else {
#pragma unroll
        for (int mt = 0; mt < 4; ++mt)
#pragma unroll
            for (int nt = 0; nt < 2; ++nt)
#pragma unroll
                for (int r = 0; r < 16; ++r) {
                    const long row = m0 + wm * 128 + mt * 32 + (r & 3) + 8 * (r >> 2) + 4 * gh;
                    const long idx = row * (long)N + (n0 + wn * 64 + nt * 32 + l31);
                    Out[idx] = (OutT)acc[mt][nt][r];
                }
    }
#undef STAGE_A
#undef STAGE_B
#undef LOAD_AB
#undef MFMA8
#undef TILE
#undef BAR
#undef LGK0
#undef VM6
#undef PRIO1
#undef PRIO0
}

extern "C" void kernel_launch(void* const* d_in, const int* in_sizes, int n_in,
                              void* d_out, int out_size, void* d_ws, size_t ws_size,
                              hipStream_t stream) {
    const float* x   = (const float*)d_in[0];
    const int*   w1c = (const int*)d_in[1];
    const float* w1s = (const float*)d_in[2];
    const int*   w2c = (const int*)d_in[3];
    const float* w2s = (const float*)d_in[4];
    const int*   w3c = (const int*)d_in[5];
    const float* w3s = (const float*)d_in[6];
    float* out = (float*)d_out;

    // workspace layout (~517 MiB): xb, w1b, w2b, w3b, h
    char* ws = (char*)d_ws;
    __bf16* xb  = (__bf16*)ws;  ws += (size_t)T_DIM * D_DIM * 2;
    __bf16* w1b = (__bf16*)ws;  ws += (size_t)H_DIM * D_DIM * 2;
    __bf16* w2b = (__bf16*)ws;  ws += (size_t)H_DIM * D_DIM * 2;
    __bf16* w3b = (__bf16*)ws;  ws += (size_t)H_DIM * D_DIM * 2;
    __bf16* hb  = (__bf16*)ws;  // T*H bf16

    const long nx = (long)T_DIM * D_DIM;   // 33,554,432
    const long nw = (long)H_DIM * D_DIM;   // 45,088,768

    cvt_f32_bf16<<<(int)(nx / (256 * 8)), 256, 0, stream>>>(x, xb, nx);
    dequant_nf4_kernel<<<(int)(nw / (256 * 8)), 256, 0, stream>>>(w1c, w1s, w1b, nw);
    dequant_nf4_kernel<<<(int)(nw / (256 * 8)), 256, 0, stream>>>(w2c, w2s, w2b, nw);
    dequant_nf4_kernel<<<(int)(nw / (256 * 8)), 256, 0, stream>>>(w3c, w3s, w3b, nw);

    // h = silu(x @ w1^T) * (x @ w2^T)   -- one fused dispatch, 256x128 tiles
    gemm_nt<D_DIM, 1, __bf16><<<dim3(H_DIM / 128, T_DIM / 256), 512, 0, stream>>>(
        xb, w1b, w2b, hb, H_DIM);
    // out = h @ w3^T
    gemm_nt<H_DIM, 0, float><<<dim3(D_DIM / 256, T_DIM / 256), 512, 0, stream>>>(
        hb, w3b, nullptr, out, D_DIM);
}

// Round 4
// 2300.075 us; speedup vs baseline: 1.1786x; 1.1786x over previous
//
#include <hip/hip_runtime.h>
#include <hip/hip_bf16.h>

// Problem dims (fixed by the reference)
#define T_DIM 8192
#define D_DIM 4096
#define H_DIM 11008

typedef __attribute__((ext_vector_type(8))) __bf16 bf16x8;
typedef __attribute__((ext_vector_type(4))) float f32x4;

typedef __attribute__((address_space(1))) const void gvoid_t;
typedef __attribute__((address_space(3))) void lvoid_t;

__device__ __forceinline__ void async_lds16(const void* g, void* l) {
    // 16B per lane, LDS dest = wave-uniform base + lane*16
    __builtin_amdgcn_global_load_lds((gvoid_t*)g, (lvoid_t*)l, 16, 0, 0);
}

__device__ const float NF4_TAB[16] = {
    -1.0f, -0.6961928009986877f, -0.5250730514526367f, -0.39491748809814453f,
    -0.28444138169288635f, -0.18477343022823334f, -0.09105003625154495f, 0.0f,
    0.07958029955625534f, 0.16093020141124725f, 0.24611230194568634f,
    0.33791524171829224f, 0.44070982933044434f, 0.5626170039176941f,
    0.7229568362236023f, 1.0f};

// ---------------- dequant: int32 codes + per-64 scalers -> bf16 ----------------
__global__ void dequant_nf4_kernel(const int* __restrict__ codes,
                                   const float* __restrict__ scalers,
                                   __bf16* __restrict__ out, long n) {
    __shared__ float tbl[16];
    if (threadIdx.x < 16) tbl[threadIdx.x] = NF4_TAB[threadIdx.x];
    __syncthreads();
    long i = ((long)blockIdx.x * blockDim.x + threadIdx.x) * 8;
    if (i >= n) return;
    float s = scalers[i >> 6];
    const int4* cp = (const int4*)(codes + i);
    int4 c0 = cp[0], c1 = cp[1];
    bf16x8 v;
    v[0] = (__bf16)(tbl[c0.x] * s);
    v[1] = (__bf16)(tbl[c0.y] * s);
    v[2] = (__bf16)(tbl[c0.z] * s);
    v[3] = (__bf16)(tbl[c0.w] * s);
    v[4] = (__bf16)(tbl[c1.x] * s);
    v[5] = (__bf16)(tbl[c1.y] * s);
    v[6] = (__bf16)(tbl[c1.z] * s);
    v[7] = (__bf16)(tbl[c1.w] * s);
    *(bf16x8*)(out + i) = v;
}

// ---------------- x: fp32 -> bf16 ----------------
__global__ void cvt_f32_bf16(const float* __restrict__ x, __bf16* __restrict__ out, long n) {
    long i = ((long)blockIdx.x * blockDim.x + threadIdx.x) * 8;
    if (i >= n) return;
    const float4* xp = (const float4*)(x + i);
    float4 f0 = xp[0], f1 = xp[1];
    bf16x8 v;
    v[0] = (__bf16)f0.x; v[1] = (__bf16)f0.y; v[2] = (__bf16)f0.z; v[3] = (__bf16)f0.w;
    v[4] = (__bf16)f1.x; v[5] = (__bf16)f1.y; v[6] = (__bf16)f1.z; v[7] = (__bf16)f1.w;
    *(bf16x8*)(out + i) = v;
}

// ============================================================================
// 256-wide deep-pipelined NT GEMM (round-2 structure: 16x16x32 MFMA, verified
// 0 bank conflicts + 51% MfmaUtil) + XCD-chunked bx-major block remap
// (round-3 verified: FETCH 3.0GB -> 1.08GB).
//
//   A [M,K] K-major, B [N,K] K-major, BK=64, 8 waves (2M x 4N), per-wave
//   output 128x64. LDS 128 KiB = 2 bufs x (A[256][64] + B[256][64]) bf16,
//   XOR-swizzled 16B blocks (block ^= row&7, applied on the pre-swizzled
//   GLOBAL source of global_load_lds; reads apply the same XOR).
//
// Per K-tile (buf X), 3 regions:
//  R1: ds_read aF[0..3],bF[0..1] (16) | stage B1(t+1)->bufY | BAR lgk0 16 MFMA BAR
//  R2: ds_read aF[4..7],bF[2..3] (16) |                      BAR lgk0 16 MFMA BAR
//  R3: stage A0,A1(t+2)->bufX | 16 MFMA | stage B0(t+2)->bufX | 16 MFMA
//      | vmcnt(6) | BAR
// Stage safety: every stage targets a region whose ds_reads were drained by a
// lgkmcnt(0) BEFORE a barrier that precedes the stage issue.
// vmcnt(6) = exactly 3 half-tiles (6 loads) in flight; leads 4-7 phases.
//
// SILU=1 (fused gate): B-tile rows interleave w1/w2 every 16 rows:
//   tile-row R <- mat=(R>>4)&1 ? B2 : B1, col = n0 + 16*(R>>5) + (R&15)
// so acc[m][0],acc[m][2] = x@w1^T and acc[m][1],acc[m][3] = x@w2^T for the
// SAME output columns -> epilogue silu(a1)*a2 is thread-local. Output tile
// 256x128 (n0 = bx*128).
//
// Block remap: XCD-chunked (bid0&7 -> xcd) AND bx-major within each chunk
// (by = xcd*Rr + j%Rr, bx = j/Rr): each B panel is fetched once per XCD and
// reused Rr x from L2; XCDs stay phase-coherent on the same bx band so L3
// serves most B traffic. Requires nwg%8==0 and (nwg/8)%gridDim.x==0
// (fused: 2752/8/86=4; out-proj: 512/8/16=4).
// ============================================================================
template<int KD, int SILU, typename OutT>
__global__ __launch_bounds__(512, 2) void gemm_nt(
    const __bf16* __restrict__ A, const __bf16* __restrict__ B1,
    const __bf16* __restrict__ B2, OutT* __restrict__ Out, const int N)
{
    static_assert(KD % 128 == 0, "need an even number of K-tiles");
    __shared__ __bf16 lds[2 * 2 * 256 * 64];   // 128 KiB

    const int tid  = threadIdx.x;
    const int lane = tid & 63;
    const int wave = tid >> 6;        // 0..7
    const int wm = wave >> 2;         // 0..1 (M half)
    const int wn = wave & 3;          // 0..3 (N quarter)

    // XCD-chunked + bx-major remap (L2 B-panel reuse)
    const int nwg  = gridDim.x * gridDim.y;
    const int bid0 = blockIdx.y * gridDim.x + blockIdx.x;
    const int q    = nwg >> 3;                 // blocks per XCD chunk
    const int Rr   = q / gridDim.x;            // tile-rows per chunk (=4 here)
    const int xcd  = bid0 & 7;
    const int j    = bid0 >> 3;
    const int by   = xcd * Rr + (j % Rr);
    const int bx   = j / Rr;
    const long m0 = (long)by * 256;
    const long n0 = (long)bx * (SILU ? 128 : 256);

    // ---- staging addressing (pre-swizzled global source, linear LDS dest) ----
    const int sr = tid >> 3;                    // row within 64-row group
    const int sb = (tid & 7) ^ (sr & 7);        // swizzled global 16B block
    const __bf16* Arow = A + (m0 + sr) * (long)KD + sb * 8;
    const __bf16* Brow;
    if (SILU) {
        // tile-row R = H*128 + a*64 + sr ; mat = bit4(sr) ; col base from sr
        const __bf16* matp = (sr & 16) ? B2 : B1;
        Brow = matp + (n0 + ((sr >> 5) << 4) + (sr & 15)) * (long)KD + sb * 8;
    } else {
        Brow = B1 + (n0 + sr) * (long)KD + sb * 8;
    }
    __bf16* dstA = &lds[(wave << 3) * 64];      // wave-uniform; +buf*32768 +h*8192
    __bf16* dstB = dstA + 16384;

    const long BH = (SILU ? 64 : 128) * (long)KD;  // B source: half-tile stride
    const long BA = (SILU ? 32 : 64) * (long)KD;   // B source: intra-half stride

#define STAGE_A(BUF, H, KT) do { \
        const __bf16* s_ = Arow + (long)(H) * 128 * KD + (long)(KT) * 64; \
        __bf16* d_ = dstA + (BUF) * 32768 + (H) * 8192; \
        async_lds16(s_, d_); \
        async_lds16(s_ + 64 * (long)KD, d_ + 4096); \
    } while (0)
#define STAGE_B(BUF, H, KT) do { \
        const __bf16* s_ = Brow + (long)(H) * BH + (long)(KT) * 64; \
        __bf16* d_ = dstB + (BUF) * 32768 + (H) * 8192; \
        async_lds16(s_, d_); \
        async_lds16(s_ + BA, d_ + 4096); \
    } while (0)

    // ---- fragment read addressing (16x16x32) ----
    const int r15 = lane & 15;
    const int hi2 = lane >> 4;
    const int l7  = lane & 7;
    const int aOff = (wm * 128 + r15) * 64;
    const int bOff = 16384 + (wn * 64 + r15) * 64;

    auto rdA = [&](int buf, int m, int kk) -> bf16x8 {
        return *(const bf16x8*)&lds[buf * 32768 + aOff + m * 1024 +
                                    (((kk * 4 + hi2) ^ l7) << 3)];
    };
    auto rdB = [&](int buf, int n, int kk) -> bf16x8 {
        return *(const bf16x8*)&lds[buf * 32768 + bOff + n * 1024 +
                                    (((kk * 4 + hi2) ^ l7) << 3)];
    };

    f32x4 acc[8][4];
    const f32x4 z4 = {0.f, 0.f, 0.f, 0.f};
#pragma unroll
    for (int m = 0; m < 8; ++m)
#pragma unroll
        for (int n = 0; n < 4; ++n) acc[m][n] = z4;

    bf16x8 aF[8][2];   // all 8 m A frags (m0-3 loaded R1, m4-7 R2)
    bf16x8 bF[4][2];   // all 4 n B frags (n0-1 R1, n2-3 R2)

#define LOAD_A4(BUF, MB) { _Pragma("unroll") for (int m_ = 0; m_ < 4; ++m_) { \
        aF[m_ + MB][0] = rdA(BUF, m_ + MB, 0); \
        aF[m_ + MB][1] = rdA(BUF, m_ + MB, 1); } }
#define LOAD_B2(BUF, NB) { _Pragma("unroll") for (int n_ = 0; n_ < 2; ++n_) { \
        bF[n_ + NB][0] = rdB(BUF, n_ + NB, 0); \
        bF[n_ + NB][1] = rdB(BUF, n_ + NB, 1); } }
#define QUAD(MB, NB) { _Pragma("unroll") for (int m_ = 0; m_ < 4; ++m_) { \
        _Pragma("unroll") for (int n_ = 0; n_ < 2; ++n_) { \
        acc[m_ + MB][n_ + NB] = __builtin_amdgcn_mfma_f32_16x16x32_bf16( \
            aF[m_ + MB][0], bF[n_ + NB][0], acc[m_ + MB][n_ + NB], 0, 0, 0); \
        acc[m_ + MB][n_ + NB] = __builtin_amdgcn_mfma_f32_16x16x32_bf16( \
            aF[m_ + MB][1], bF[n_ + NB][1], acc[m_ + MB][n_ + NB], 0, 0, 0); } } }
#define BAR()  __builtin_amdgcn_s_barrier()
#define LGK0() asm volatile("s_waitcnt lgkmcnt(0)" ::: "memory")
#define VM6()  asm volatile("s_waitcnt vmcnt(6)" ::: "memory")
#define PRIO1() __builtin_amdgcn_s_setprio(1)
#define PRIO0() __builtin_amdgcn_s_setprio(0)

    // One K-tile in BUF; stages B1(T1)->other buf (lead 4), A+B0(T2)->BUF
    // (leads 5-7). vmcnt(6) leaves exactly {A0,A1,B0}(T2) = 6 loads in flight.
#define TILE(BUF, T1, T2) \
    LOAD_A4(BUF, 0); LOAD_B2(BUF, 0); \
    STAGE_B(1 - (BUF), 1, T1); \
    BAR(); LGK0(); PRIO1(); QUAD(0, 0); PRIO0(); BAR(); \
    LOAD_A4(BUF, 4); LOAD_B2(BUF, 2); \
    BAR(); LGK0(); PRIO1(); QUAD(0, 2); PRIO0(); BAR(); \
    STAGE_A(BUF, 0, T2); STAGE_A(BUF, 1, T2); \
    PRIO1(); QUAD(4, 2); PRIO0(); \
    STAGE_B(BUF, 0, T2); \
    PRIO1(); QUAD(4, 0); PRIO0(); \
    VM6(); BAR();

    const int NT = KD / 64;

    // ---- prologue: tile0 complete -> buf0; A0,A1,B0 of tile1 -> buf1 ----
    STAGE_A(0, 0, 0); STAGE_A(0, 1, 0);
    STAGE_B(0, 0, 0); STAGE_B(0, 1, 0);
    STAGE_A(1, 0, 1); STAGE_A(1, 1, 1);
    STAGE_B(1, 0, 1);
    VM6();            // 14 issued, drain to 6 -> tile0's 8 loads landed
    BAR();

#pragma unroll 1
    for (int t = 0; t < NT; t += 2) {
        const int t1 = t + 1;
        int t2 = t + 2; if (t2 >= NT) t2 -= NT;   // wrap: tail prefetch is
        int t3 = t + 3; if (t3 >= NT) t3 -= NT;   // harmless (never read)
        TILE(0, t1, t2);
        TILE(1, t2, t3);
    }
    asm volatile("s_waitcnt vmcnt(0)" ::: "memory");  // drain tail prefetches

    // ---- epilogue: 16x16 C/D layout col=lane&15, row=(lane>>4)*4+reg ----
    const int crow = hi2 * 4;
    if (SILU) {
#pragma unroll
        for (int m = 0; m < 8; ++m)
#pragma unroll
            for (int p = 0; p < 2; ++p)
#pragma unroll
                for (int r = 0; r < 4; ++r) {
                    const long row = m0 + wm * 128 + m * 16 + crow + r;
                    const long idx = row * (long)N + (n0 + wn * 32 + p * 16 + r15);
                    float a = acc[m][2 * p][r];      // x @ w1^T
                    float b = acc[m][2 * p + 1][r];  // x @ w2^T
                    float sg = 1.0f / (1.0f + __expf(-a));
                    Out[idx] = (OutT)(a * sg * b);
                }
    } else {
#pragma unroll
        for (int m = 0; m < 8; ++m)
#pragma unroll
            for (int n = 0; n < 4; ++n)
#pragma unroll
                for (int r = 0; r < 4; ++r) {
                    const long row = m0 + wm * 128 + m * 16 + crow + r;
                    const long idx = row * (long)N + (n0 + wn * 64 + n * 16 + r15);
                    Out[idx] = (OutT)acc[m][n][r];
                }
    }
#undef STAGE_A
#undef STAGE_B
#undef LOAD_A4
#undef LOAD_B2
#undef QUAD
#undef TILE
#undef BAR
#undef LGK0
#undef VM6
#undef PRIO1
#undef PRIO0
}

extern "C" void kernel_launch(void* const* d_in, const int* in_sizes, int n_in,
                              void* d_out, int out_size, void* d_ws, size_t ws_size,
                              hipStream_t stream) {
    const float* x   = (const float*)d_in[0];
    const int*   w1c = (const int*)d_in[1];
    const float* w1s = (const float*)d_in[2];
    const int*   w2c = (const int*)d_in[3];
    const float* w2s = (const float*)d_in[4];
    const int*   w3c = (const int*)d_in[5];
    const float* w3s = (const float*)d_in[6];
    float* out = (float*)d_out;

    // workspace layout (~517 MiB): xb, w1b, w2b, w3b, h
    char* ws = (char*)d_ws;
    __bf16* xb  = (__bf16*)ws;  ws += (size_t)T_DIM * D_DIM * 2;
    __bf16* w1b = (__bf16*)ws;  ws += (size_t)H_DIM * D_DIM * 2;
    __bf16* w2b = (__bf16*)ws;  ws += (size_t)H_DIM * D_DIM * 2;
    __bf16* w3b = (__bf16*)ws;  ws += (size_t)H_DIM * D_DIM * 2;
    __bf16* hb  = (__bf16*)ws;  // T*H bf16

    const long nx = (long)T_DIM * D_DIM;   // 33,554,432
    const long nw = (long)H_DIM * D_DIM;   // 45,088,768

    cvt_f32_bf16<<<(int)(nx / (256 * 8)), 256, 0, stream>>>(x, xb, nx);
    dequant_nf4_kernel<<<(int)(nw / (256 * 8)), 256, 0, stream>>>(w1c, w1s, w1b, nw);
    dequant_nf4_kernel<<<(int)(nw / (256 * 8)), 256, 0, stream>>>(w2c, w2s, w2b, nw);
    dequant_nf4_kernel<<<(int)(nw / (256 * 8)), 256, 0, stream>>>(w3c, w3s, w3b, nw);

    // h = silu(x @ w1^T) * (x @ w2^T)   -- one fused dispatch, 256x128 tiles
    gemm_nt<D_DIM, 1, __bf16><<<dim3(H_DIM / 128, T_DIM / 256), 512, 0, stream>>>(
        xb, w1b, w2b, hb, H_DIM);
    // out = h @ w3^T
    gemm_nt<H_DIM, 0, float><<<dim3(D_DIM / 256, T_DIM / 256), 512, 0, stream>>>(
        hb, w3b, nullptr, out, D_DIM);
}